// Round 1
// baseline (1068.662 us; speedup 1.0000x reference)
//
#include <hip/hip_runtime.h>
#include <cstdint>

#define BATCH 4
#define CIN   256
#define COUT  256
#define HH    96
#define WW    96
#define HWSZ  (HH*WW)      // 9216
#define KT    9
#define TP    16
#define GN_G  16
#define EPSV  1e-5f

// ---- weight repack: [cout][cin][3][3] -> [k][cin][cout] (coalesced GEMM loads)
__global__ void repack_w_kernel(const float* __restrict__ w, float* __restrict__ wt) {
    int dst = blockIdx.x * 256 + threadIdx.x;   // dst = k<<16 | cin<<8 | cout
    int cout = dst & 255;
    int cin  = (dst >> 8) & 255;
    int k    = dst >> 16;
    wt[dst] = w[cout * (CIN * 9) + cin * 9 + k];
}

// ---- deformable conv, fp32 baseline
__global__ __launch_bounds__(256)
void dcn_conv_kernel(const float* __restrict__ x, const float* __restrict__ off,
                     const float* __restrict__ msk, const float* __restrict__ wt,
                     float* __restrict__ out) {
    __shared__ int   s_idx[KT][TP][4];
    __shared__ float s_wgt[KT][TP][4];
    __shared__ __align__(16) float s_val[CIN][20];   // pad 16->20: 16B-aligned rows, spread banks

    const int b  = blockIdx.y;
    const int p0 = blockIdx.x * TP;
    const int t  = threadIdx.x;

    // Phase A: per (tap, position) sampling coords + fused (bilinear * mask * valid) weights
    if (t < KT * TP) {
        const int k = t >> 4, p = t & 15;
        const int pos = p0 + p;
        const int h = pos / WW, w = pos % WW;
        const float oy = off[((size_t)b * 18 + 2 * k) * HWSZ + pos];
        const float ox = off[((size_t)b * 18 + 2 * k + 1) * HWSZ + pos];
        const float m  = msk[((size_t)b * 9 + k) * HWSZ + pos];
        const float py = (float)(h + k / 3 - 1) + oy;
        const float px = (float)(w + k % 3 - 1) + ox;
        const float y0 = floorf(py), x0 = floorf(px);
        #pragma unroll
        for (int dy = 0; dy < 2; ++dy)
        #pragma unroll
        for (int dx = 0; dx < 2; ++dx) {
            const float yy = y0 + (float)dy, xx = x0 + (float)dx;
            const float wb = (1.f - fabsf(py - yy)) * (1.f - fabsf(px - xx));
            const bool valid = (yy >= 0.f) && (yy < (float)HH) && (xx >= 0.f) && (xx < (float)WW);
            int yi = (int)yy; yi = yi < 0 ? 0 : (yi > HH - 1 ? HH - 1 : yi);
            int xi = (int)xx; xi = xi < 0 ? 0 : (xi > WW - 1 ? WW - 1 : xi);
            s_idx[k][p][dy * 2 + dx] = yi * WW + xi;
            s_wgt[k][p][dy * 2 + dx] = valid ? wb * m : 0.f;
        }
    }
    __syncthreads();

    float acc[TP];
    #pragma unroll
    for (int p = 0; p < TP; ++p) acc[p] = 0.f;

    const float* xb = x + (size_t)b * CIN * HWSZ;
    const int cout = t;

    for (int k = 0; k < KT; ++k) {
        // Stage sampled+modulated values for all CIN channels at this tap.
        // thread -> (p = t&15, cb = t>>4); 16 lanes share a channel => coalesced-ish gathers
        {
            const int p  = t & 15;
            const int cb = t >> 4;
            const int i0 = s_idx[k][p][0], i1 = s_idx[k][p][1];
            const int i2 = s_idx[k][p][2], i3 = s_idx[k][p][3];
            const float w0 = s_wgt[k][p][0], w1 = s_wgt[k][p][1];
            const float w2 = s_wgt[k][p][2], w3 = s_wgt[k][p][3];
            #pragma unroll
            for (int i = 0; i < 16; ++i) {
                const int c = cb + (i << 4);
                const float* xc = xb + (size_t)c * HWSZ;
                s_val[c][p] = w0 * xc[i0] + w1 * xc[i1] + w2 * xc[i2] + w3 * xc[i3];
            }
        }
        __syncthreads();

        // GEMM slice: acc[p] += W[cout, c, k] * val[c][p]
        const float* wk = wt + ((size_t)k << 16) + cout;
        #pragma unroll 4
        for (int c = 0; c < CIN; ++c) {
            const float wv = wk[(size_t)c << 8];      // coalesced across lanes, L2-resident
            const float* vr = &s_val[c][0];
            const float4 v0 = *(const float4*)(vr);
            const float4 v1 = *(const float4*)(vr + 4);
            const float4 v2 = *(const float4*)(vr + 8);
            const float4 v3 = *(const float4*)(vr + 12);
            acc[0]  += wv * v0.x; acc[1]  += wv * v0.y; acc[2]  += wv * v0.z; acc[3]  += wv * v0.w;
            acc[4]  += wv * v1.x; acc[5]  += wv * v1.y; acc[6]  += wv * v1.z; acc[7]  += wv * v1.w;
            acc[8]  += wv * v2.x; acc[9]  += wv * v2.y; acc[10] += wv * v2.z; acc[11] += wv * v2.w;
            acc[12] += wv * v3.x; acc[13] += wv * v3.y; acc[14] += wv * v3.z; acc[15] += wv * v3.w;
        }
        __syncthreads();
    }

    float* orow = out + ((size_t)b * COUT + cout) * HWSZ + p0;
    *(float4*)(orow + 0)  = make_float4(acc[0],  acc[1],  acc[2],  acc[3]);
    *(float4*)(orow + 4)  = make_float4(acc[4],  acc[5],  acc[6],  acc[7]);
    *(float4*)(orow + 8)  = make_float4(acc[8],  acc[9],  acc[10], acc[11]);
    *(float4*)(orow + 12) = make_float4(acc[12], acc[13], acc[14], acc[15]);
}

// ---- GroupNorm stats: one block per (batch, group)
__global__ __launch_bounds__(256)
void gn_stats_kernel(const float* __restrict__ y, float* __restrict__ stats) {
    const int bg = blockIdx.x;                 // b*16 + g
    const int t  = threadIdx.x;
    const float* base = y + (size_t)bg * (COUT / GN_G) * HWSZ;
    const int n4 = (COUT / GN_G) * HWSZ / 4;   // 36864 float4s
    float s = 0.f, q = 0.f;
    for (int i = t; i < n4; i += 256) {
        const float4 v = ((const float4*)base)[i];
        s += v.x + v.y + v.z + v.w;
        q += v.x * v.x + v.y * v.y + v.z * v.z + v.w * v.w;
    }
    __shared__ float rs[256], rq[256];
    rs[t] = s; rq[t] = q;
    __syncthreads();
    for (int o = 128; o > 0; o >>= 1) {
        if (t < o) { rs[t] += rs[t + o]; rq[t] += rq[t + o]; }
        __syncthreads();
    }
    if (t == 0) {
        const float invn = 1.f / (float)((COUT / GN_G) * HWSZ);
        const float mean = rs[0] * invn;
        const float var  = rq[0] * invn - mean * mean;
        stats[bg * 2]     = mean;
        stats[bg * 2 + 1] = var;
    }
}

// ---- GroupNorm apply (in place on d_out)
__global__ __launch_bounds__(256)
void gn_apply_kernel(float* __restrict__ y, const float* __restrict__ stats,
                     const float* __restrict__ gamma, const float* __restrict__ beta) {
    const int i = blockIdx.x * 256 + threadIdx.x;       // float4 index
    const int e = i * 4;
    const int c  = (e / HWSZ) & (COUT - 1);
    const int bg = e / (HWSZ * (COUT / GN_G));
    const float mean = stats[bg * 2];
    const float var  = stats[bg * 2 + 1];
    const float sc = rsqrtf(var + EPSV) * gamma[c];
    const float sh = beta[c] - mean * rsqrtf(var + EPSV) * gamma[c];
    float4 v = ((float4*)y)[i];
    v.x = v.x * sc + sh;
    v.y = v.y * sc + sh;
    v.z = v.z * sc + sh;
    v.w = v.w * sc + sh;
    ((float4*)y)[i] = v;
}

extern "C" void kernel_launch(void* const* d_in, const int* in_sizes, int n_in,
                              void* d_out, int out_size, void* d_ws, size_t ws_size,
                              hipStream_t stream) {
    const float* x      = (const float*)d_in[0];
    const float* offset = (const float*)d_in[1];
    const float* mask   = (const float*)d_in[2];
    const float* weight = (const float*)d_in[3];
    const float* gamma  = (const float*)d_in[4];
    const float* beta   = (const float*)d_in[5];
    float* out = (float*)d_out;

    float* wt2   = (float*)d_ws;                       // 9*256*256 floats = 2.36 MB
    float* stats = (float*)d_ws + KT * CIN * COUT;     // 128 floats

    repack_w_kernel<<<KT * CIN * COUT / 256, 256, 0, stream>>>(weight, wt2);

    dim3 grid(HWSZ / TP, BATCH);
    dcn_conv_kernel<<<grid, 256, 0, stream>>>(x, offset, mask, wt2, out);

    gn_stats_kernel<<<BATCH * GN_G, 256, 0, stream>>>(out, stats);

    gn_apply_kernel<<<(size_t)BATCH * COUT * HWSZ / 4 / 256, 256, 0, stream>>>(out, stats, gamma, beta);
}

// Round 2
// 261.168 us; speedup vs baseline: 4.0919x; 4.0919x over previous
//
#include <hip/hip_runtime.h>
#include <cstdint>

typedef short  short8  __attribute__((ext_vector_type(8)));
typedef ushort ushort8 __attribute__((ext_vector_type(8)));
typedef float  f32x4   __attribute__((ext_vector_type(4)));

#define BATCH 4
#define CIN   256
#define COUT  256
#define HH    96
#define WW    96
#define HWSZ  (HH*WW)      // 9216
#define GN_G  16
#define EPSV  1e-5f
#define BN    64           // positions per block
#define STR   264          // LDS row stride in bf16 (256 + 8 pad -> 2-way banks, free)
#define GN_PART 16         // partial-sum blocks per (b,group)

__device__ __forceinline__ float bf2f(ushort u) {
    return __uint_as_float(((uint32_t)u) << 16);
}
__device__ __forceinline__ ushort f2bf(float f) {
    uint32_t u = __float_as_uint(f);
    u += 0x7FFFu + ((u >> 16) & 1u);   // round-to-nearest-even
    return (ushort)(u >> 16);
}

// ---- x: [b][c][p] fp32 -> xn: [b][p][c] bf16 (tiled transpose via LDS)
__global__ __launch_bounds__(256)
void nhwc_kernel(const float* __restrict__ x, ushort* __restrict__ xn) {
    __shared__ ushort tile[64][66];
    const int b  = blockIdx.z;
    const int cb = blockIdx.y * 64;
    const int pb = blockIdx.x * 64;
    const int t  = threadIdx.x;
    {
        const int pl = t & 63;
        const int cq = t >> 6;           // 0..3
        #pragma unroll
        for (int i = 0; i < 16; ++i) {
            const int c = cq * 16 + i;
            tile[c][pl] = f2bf(x[((size_t)b * CIN + cb + c) * HWSZ + pb + pl]);
        }
    }
    __syncthreads();
    {
        const int cl = t & 63;
        const int pq = t >> 6;
        #pragma unroll
        for (int i = 0; i < 16; ++i) {
            const int p = pq * 16 + i;
            xn[((size_t)b * HWSZ + pb + p) * CIN + cb + cl] = tile[cl][p];
        }
    }
}

// ---- weight [cout][cin][3][3] fp32 -> Wp[kb8][cout][8] bf16, globalK = tap*256 + cin
__global__ __launch_bounds__(256)
void repack_w_kernel(const float* __restrict__ w, ushort* __restrict__ wp) {
    const int d    = blockIdx.x * 256 + threadIdx.x;     // 0 .. 2304*256-1
    const int j    = d & 7;
    const int cout = (d >> 3) & 255;
    const int kb8  = d >> 11;
    const int ktap = kb8 >> 5;
    const int cin  = ((kb8 & 31) << 3) | j;
    wp[d] = f2bf(w[cout * (CIN * 9) + cin * 9 + ktap]);
}

// ---- fused deformable-conv GEMM: out[b][cout][pos], bf16 MFMA, fp32 accum
__global__ __launch_bounds__(256)
void dcn_mfma_kernel(const ushort* __restrict__ xn, const float* __restrict__ off,
                     const float* __restrict__ msk, const ushort* __restrict__ wp,
                     float* __restrict__ out) {
    __shared__ ushort sval[2][BN * STR];   // 2 x 33.8 KB double buffer

    const int b    = blockIdx.y;
    const int p0   = blockIdx.x * BN;
    const int t    = threadIdx.x;
    const int lane = t & 63;
    const int wid  = t >> 6;

    f32x4 acc[4][4];
    #pragma unroll
    for (int i = 0; i < 4; ++i)
        #pragma unroll
        for (int j = 0; j < 4; ++j)
            acc[i][j] = (f32x4){0.f, 0.f, 0.f, 0.f};

    // ---- stage: bilinear sample tap k of all 256 cin x 64 pos into buf (bf16)
    auto stage = [&](int k, ushort* buf) {
        const int pl  = t >> 2;            // 0..63 position
        const int sub = t & 3;             // channel quarter (64 ch)
        const int pos = p0 + pl;
        const int hh  = pos / WW;
        const int ww  = pos - hh * WW;
        const size_t obase = ((size_t)b * 18 + 2 * k) * HWSZ + pos;
        const float oy = off[obase];
        const float ox = off[obase + HWSZ];
        const float m  = msk[((size_t)b * 9 + k) * HWSZ + pos];
        const float py = (float)(hh + k / 3 - 1) + oy;
        const float px = (float)(ww + k % 3 - 1) + ox;
        const float y0 = floorf(py), x0 = floorf(px);
        int   idx[4];
        float wgt[4];
        #pragma unroll
        for (int dy = 0; dy < 2; ++dy)
            #pragma unroll
            for (int dx = 0; dx < 2; ++dx) {
                const float yy = y0 + (float)dy, xx = x0 + (float)dx;
                const float wb = (1.f - fabsf(py - yy)) * (1.f - fabsf(px - xx));
                const bool valid = (yy >= 0.f) && (yy < (float)HH) && (xx >= 0.f) && (xx < (float)WW);
                int yi = (int)yy; yi = yi < 0 ? 0 : (yi > HH - 1 ? HH - 1 : yi);
                int xi = (int)xx; xi = xi < 0 ? 0 : (xi > WW - 1 ? WW - 1 : xi);
                idx[dy * 2 + dx] = yi * WW + xi;
                wgt[dy * 2 + dx] = valid ? wb * m : 0.f;
            }
        const ushort* xb = xn + (size_t)b * HWSZ * CIN + sub * 64;
        ushort* dst = buf + pl * STR + sub * 64;
        #pragma unroll
        for (int ch = 0; ch < 64; ch += 8) {
            const ushort8 v0 = *(const ushort8*)(xb + (size_t)idx[0] * CIN + ch);
            const ushort8 v1 = *(const ushort8*)(xb + (size_t)idx[1] * CIN + ch);
            const ushort8 v2 = *(const ushort8*)(xb + (size_t)idx[2] * CIN + ch);
            const ushort8 v3 = *(const ushort8*)(xb + (size_t)idx[3] * CIN + ch);
            ushort8 o;
            #pragma unroll
            for (int j = 0; j < 8; ++j) {
                const float a = wgt[0] * bf2f(v0[j]) + wgt[1] * bf2f(v1[j])
                              + wgt[2] * bf2f(v2[j]) + wgt[3] * bf2f(v3[j]);
                o[j] = f2bf(a);
            }
            *(ushort8*)(dst + ch) = o;
        }
    };

    // ---- MFMA over one tap (K=256) from buf
    auto mfma_tap = [&](int k, const ushort* buf) {
        const int arow  = lane & 15;       // m within 16 (A) / n within 16 (B)
        const int akb   = lane >> 4;       // k-quadrant
        const int mbase = wid * 64;
        const ushort* bbase = buf + arow * STR + akb * 8;
        #pragma unroll
        for (int ks = 0; ks < 8; ++ks) {
            short8 af[4], bfr[4];
            const size_t kb8 = (size_t)(k * 32 + ks * 4 + akb);
            const ushort* wrow = wp + (kb8 * COUT + mbase + arow) * 8;
            #pragma unroll
            for (int mt = 0; mt < 4; ++mt)
                af[mt] = *(const short8*)(wrow + mt * 16 * 8);
            #pragma unroll
            for (int nt = 0; nt < 4; ++nt)
                bfr[nt] = *(const short8*)(bbase + nt * 16 * STR + ks * 32);
            #pragma unroll
            for (int mt = 0; mt < 4; ++mt)
                #pragma unroll
                for (int nt = 0; nt < 4; ++nt)
                    acc[mt][nt] = __builtin_amdgcn_mfma_f32_16x16x32_bf16(
                        af[mt], bfr[nt], acc[mt][nt], 0, 0, 0);
        }
    };

    stage(0, sval[0]);
    __syncthreads();
    int cur = 0;
    for (int k = 0; k < 9; ++k) {
        if (k < 8) stage(k + 1, sval[cur ^ 1]);   // issue next-tap gathers first
        mfma_tap(k, sval[cur]);
        __syncthreads();
        cur ^= 1;
    }

    // ---- epilogue: C/D layout col=lane&15 (pos), row=(lane>>4)*4+r (cout)
    const int prow = lane & 15;
    const int crow = (lane >> 4) * 4;
    #pragma unroll
    for (int mt = 0; mt < 4; ++mt) {
        const int cout = wid * 64 + mt * 16 + crow;
        #pragma unroll
        for (int nt = 0; nt < 4; ++nt) {
            const int pos = p0 + nt * 16 + prow;
            float* op = out + ((size_t)b * COUT + cout) * HWSZ + pos;
            #pragma unroll
            for (int r = 0; r < 4; ++r)
                op[(size_t)r * HWSZ] = acc[mt][nt][r];
        }
    }
}

// ---- GroupNorm partial sums: grid (GN_PART, B*GN_G)
__global__ __launch_bounds__(256)
void gn_part_kernel(const float* __restrict__ y, float* __restrict__ part) {
    const int bg = blockIdx.y;
    const int pp = blockIdx.x;
    const int t  = threadIdx.x;
    const int chunk = (COUT / GN_G) * HWSZ / GN_PART;          // 9216 floats
    const float* base = y + (size_t)bg * (COUT / GN_G) * HWSZ + (size_t)pp * chunk;
    float s = 0.f, q = 0.f;
    for (int i = t; i < chunk / 4; i += 256) {
        const float4 v = ((const float4*)base)[i];
        s += v.x + v.y + v.z + v.w;
        q += v.x * v.x + v.y * v.y + v.z * v.z + v.w * v.w;
    }
    __shared__ float rs[256], rq[256];
    rs[t] = s; rq[t] = q;
    __syncthreads();
    for (int o = 128; o > 0; o >>= 1) {
        if (t < o) { rs[t] += rs[t + o]; rq[t] += rq[t + o]; }
        __syncthreads();
    }
    if (t == 0) {
        part[(bg * GN_PART + pp) * 2]     = rs[0];
        part[(bg * GN_PART + pp) * 2 + 1] = rq[0];
    }
}

// ---- reduce partials -> stats[bg] = {mean, var}; 1 block, 64 threads
__global__ void gn_final_kernel(const float* __restrict__ part, float* __restrict__ stats) {
    const int bg = threadIdx.x;
    if (bg >= BATCH * GN_G) return;
    float s = 0.f, q = 0.f;
    for (int i = 0; i < GN_PART; ++i) {
        s += part[(bg * GN_PART + i) * 2];
        q += part[(bg * GN_PART + i) * 2 + 1];
    }
    const float invn = 1.f / (float)((COUT / GN_G) * HWSZ);
    const float mean = s * invn;
    stats[bg * 2]     = mean;
    stats[bg * 2 + 1] = q * invn - mean * mean;
}

// ---- GroupNorm apply (in place)
__global__ __launch_bounds__(256)
void gn_apply_kernel(float* __restrict__ y, const float* __restrict__ stats,
                     const float* __restrict__ gamma, const float* __restrict__ beta) {
    const int i = blockIdx.x * 256 + threadIdx.x;       // float4 index
    const int e = i * 4;
    const int c  = (e / HWSZ) & (COUT - 1);
    const int bg = e / (HWSZ * (COUT / GN_G));
    const float mean = stats[bg * 2];
    const float var  = stats[bg * 2 + 1];
    const float inv  = rsqrtf(var + EPSV);
    const float sc = inv * gamma[c];
    const float sh = beta[c] - mean * sc;
    float4 v = ((float4*)y)[i];
    v.x = v.x * sc + sh;
    v.y = v.y * sc + sh;
    v.z = v.z * sc + sh;
    v.w = v.w * sc + sh;
    ((float4*)y)[i] = v;
}

extern "C" void kernel_launch(void* const* d_in, const int* in_sizes, int n_in,
                              void* d_out, int out_size, void* d_ws, size_t ws_size,
                              hipStream_t stream) {
    const float* x      = (const float*)d_in[0];
    const float* offset = (const float*)d_in[1];
    const float* mask   = (const float*)d_in[2];
    const float* weight = (const float*)d_in[3];
    const float* gamma  = (const float*)d_in[4];
    const float* beta   = (const float*)d_in[5];
    float* out = (float*)d_out;

    // ws layout: xn bf16 (18.9 MB) | wp bf16 (1.18 MB) | part (2 KB) | stats (512 B)
    ushort* xn    = (ushort*)d_ws;
    ushort* wp    = xn + (size_t)BATCH * HWSZ * CIN;
    float*  part  = (float*)(wp + (size_t)9 * CIN * COUT);
    float*  stats = part + BATCH * GN_G * GN_PART * 2;

    {
        dim3 g(HWSZ / 64, CIN / 64, BATCH);
        nhwc_kernel<<<g, 256, 0, stream>>>(x, xn);
    }
    repack_w_kernel<<<9 * CIN * COUT / 256, 256, 0, stream>>>(weight, wp);
    {
        dim3 g(HWSZ / BN, BATCH);
        dcn_mfma_kernel<<<g, 256, 0, stream>>>(xn, offset, mask, wp, out);
    }
    {
        dim3 g(GN_PART, BATCH * GN_G);
        gn_part_kernel<<<g, 256, 0, stream>>>(out, part);
    }
    gn_final_kernel<<<1, 64, 0, stream>>>(part, stats);
    gn_apply_kernel<<<(size_t)BATCH * COUT * HWSZ / 4 / 256, 256, 0, stream>>>(out, stats, gamma, beta);
}

// Round 3
// 193.573 us; speedup vs baseline: 5.5207x; 1.3492x over previous
//
#include <hip/hip_runtime.h>
#include <cstdint>

typedef short  short8  __attribute__((ext_vector_type(8)));
typedef ushort ushort8 __attribute__((ext_vector_type(8)));
typedef float  f32x4   __attribute__((ext_vector_type(4)));

#define BATCH 4
#define CIN   256
#define COUT  256
#define HH    96
#define WW    96
#define HWSZ  9216
#define GN_G  16
#define EPSV  1e-5f
#define BN    64            // positions per block
#define NPB   144           // position-blocks per batch (9216/64)
#define NWG   (BATCH*NPB)   // 576 blocks, %8==0 -> bijective XCD swizzle

__device__ __forceinline__ float bf2f(ushort u) {
    return __uint_as_float(((uint32_t)u) << 16);
}
__device__ __forceinline__ ushort f2bf(float f) {
    uint32_t u = __float_as_uint(f);
    u += 0x7FFFu + ((u >> 16) & 1u);   // round-to-nearest-even
    return (ushort)(u >> 16);
}

// ---- x: [b][c][p] fp32 -> xn: [b][p][c] bf16 (tiled transpose via LDS)
__global__ __launch_bounds__(256)
void nhwc_kernel(const float* __restrict__ x, ushort* __restrict__ xn) {
    __shared__ ushort tile[64][66];
    const int b  = blockIdx.z;
    const int cb = blockIdx.y * 64;
    const int pb = blockIdx.x * 64;
    const int t  = threadIdx.x;
    {
        const int pl = t & 63;
        const int cq = t >> 6;
        #pragma unroll
        for (int i = 0; i < 16; ++i) {
            const int c = cq * 16 + i;
            tile[c][pl] = f2bf(x[((size_t)b * CIN + cb + c) * HWSZ + pb + pl]);
        }
    }
    __syncthreads();
    {
        const int cl = t & 63;
        const int pq = t >> 6;
        #pragma unroll
        for (int i = 0; i < 16; ++i) {
            const int p = pq * 16 + i;
            xn[((size_t)b * HWSZ + pb + p) * CIN + cb + cl] = tile[cl][p];
        }
    }
}

// ---- weight [cout][cin][3][3] fp32 -> Wp[kb8][cout][8] bf16, globalK = tap*256 + cin
__global__ __launch_bounds__(256)
void repack_w_kernel(const float* __restrict__ w, ushort* __restrict__ wp) {
    const int d    = blockIdx.x * 256 + threadIdx.x;
    const int j    = d & 7;
    const int cout = (d >> 3) & 255;
    const int kb8  = d >> 11;
    const int ktap = kb8 >> 5;
    const int cin  = ((kb8 & 31) << 3) | j;
    wp[d] = f2bf(w[cout * (CIN * 9) + cin * 9 + ktap]);
}

// ---- fused deformable-conv GEMM + GN partial stats
__global__ __launch_bounds__(256, 4)
void dcn_mfma_kernel(const ushort* __restrict__ xn, const float* __restrict__ off,
                     const float* __restrict__ msk, const ushort* __restrict__ wp,
                     float* __restrict__ out, float* __restrict__ part) {
    __shared__ ushort buf[2][BN * 128];   // 2 x 16 KB, swizzled 256B rows

    const int bid  = blockIdx.x;
    const int swz  = (bid & 7) * (NWG / 8) + (bid >> 3);   // XCD-contiguous chunks
    const int b    = swz / NPB;
    const int pblk = swz - b * NPB;
    const int p0   = pblk * BN;

    const int t    = threadIdx.x;
    const int lane = t & 63;
    const int wid  = t >> 6;

    // staging role: row (position) pl, channel quarter sub (32 ch)
    const int pl  = (t & 15) | (wid << 4);
    const int sub = (t >> 4) & 3;
    const int pos = p0 + pl;
    const int hh  = pos / WW;
    const int ww  = pos - hh * WW;

    int   sidx[4];
    float swgt[4];

    auto coords = [&](int k) {
        const size_t obase = ((size_t)b * 18 + 2 * k) * HWSZ + pos;
        const float oy = off[obase];
        const float ox = off[obase + HWSZ];
        const float m  = msk[((size_t)b * 9 + k) * HWSZ + pos];
        const float py = (float)(hh + k / 3 - 1) + oy;
        const float px = (float)(ww + k % 3 - 1) + ox;
        const float y0 = floorf(py), x0 = floorf(px);
        #pragma unroll
        for (int dy = 0; dy < 2; ++dy)
            #pragma unroll
            for (int dx = 0; dx < 2; ++dx) {
                const float yy = y0 + (float)dy, xx = x0 + (float)dx;
                const float wb = (1.f - fabsf(py - yy)) * (1.f - fabsf(px - xx));
                const bool valid = (yy >= 0.f) && (yy < (float)HH) && (xx >= 0.f) && (xx < (float)WW);
                int yi = (int)yy; yi = yi < 0 ? 0 : (yi > HH - 1 ? HH - 1 : yi);
                int xi = (int)xx; xi = xi < 0 ? 0 : (xi > WW - 1 ? WW - 1 : xi);
                sidx[dy * 2 + dx] = yi * WW + xi;
                swgt[dy * 2 + dx] = valid ? wb * m : 0.f;
            }
    };

    // stage one 128-channel half-tap: rows=pos (256B), col byte ^= (row&15)<<4
    auto stage = [&](int half, ushort* dst) {
        const ushort* xb = xn + (size_t)b * HWSZ * CIN + half * 128 + sub * 32;
        char* drow = (char*)dst + pl * 256;
        const int sw = (pl & 15) << 4;
        #pragma unroll
        for (int it = 0; it < 4; ++it) {
            const ushort8 v0 = *(const ushort8*)(xb + (size_t)sidx[0] * CIN + it * 8);
            const ushort8 v1 = *(const ushort8*)(xb + (size_t)sidx[1] * CIN + it * 8);
            const ushort8 v2 = *(const ushort8*)(xb + (size_t)sidx[2] * CIN + it * 8);
            const ushort8 v3 = *(const ushort8*)(xb + (size_t)sidx[3] * CIN + it * 8);
            ushort8 o;
            #pragma unroll
            for (int j = 0; j < 8; ++j)
                o[j] = f2bf(swgt[0] * bf2f(v0[j]) + swgt[1] * bf2f(v1[j])
                          + swgt[2] * bf2f(v2[j]) + swgt[3] * bf2f(v3[j]));
            *(ushort8*)(drow + ((sub * 64 + it * 16) ^ sw)) = o;
        }
    };

    f32x4 acc[4][4];
    #pragma unroll
    for (int i = 0; i < 4; ++i)
        #pragma unroll
        for (int j = 0; j < 4; ++j)
            acc[i][j] = (f32x4){0.f, 0.f, 0.f, 0.f};

    const int arow = lane & 15;
    const int akb  = lane >> 4;
    const int asw  = arow << 4;

    auto mfma_chunk = [&](int kb8base, const ushort* src) {
        const char* srow = (const char*)src;
        #pragma unroll
        for (int ks = 0; ks < 4; ++ks) {
            short8 af[4], bfr[4];
            const ushort* wrow = wp + ((size_t)(kb8base + ks * 4 + akb) * COUT + wid * 64 + arow) * 8;
            #pragma unroll
            for (int mt = 0; mt < 4; ++mt)
                af[mt] = *(const short8*)(wrow + mt * 16 * 8);
            const int cb = (ks * 64 + akb * 16) ^ asw;
            #pragma unroll
            for (int nt = 0; nt < 4; ++nt)
                bfr[nt] = *(const short8*)(srow + (arow + nt * 16) * 256 + cb);
            #pragma unroll
            for (int mt = 0; mt < 4; ++mt)
                #pragma unroll
                for (int nt = 0; nt < 4; ++nt)
                    acc[mt][nt] = __builtin_amdgcn_mfma_f32_16x16x32_bf16(
                        af[mt], bfr[nt], acc[mt][nt], 0, 0, 0);
        }
    };

    coords(0);
    stage(0, buf[0]);
    __syncthreads();
    int cur = 0;
    #pragma unroll 2
    for (int c = 0; c < 18; ++c) {
        if (c < 17) {
            const int nc = c + 1;
            if (!(nc & 1)) coords(nc >> 1);
            stage(nc & 1, buf[cur ^ 1]);      // issue next-chunk gathers before MFMA
        }
        mfma_chunk(c * 16, buf[cur]);
        __syncthreads();
        cur ^= 1;
    }

    // ---- epilogue: C/D layout col=lane&15 (pos), row=(lane>>4)*4+r (cout)
    const int prow = lane & 15;
    const int crow = (lane >> 4) * 4;
    #pragma unroll
    for (int mt = 0; mt < 4; ++mt) {
        const int cout = wid * 64 + mt * 16 + crow;
        #pragma unroll
        for (int nt = 0; nt < 4; ++nt) {
            const int opos = p0 + nt * 16 + prow;
            float* op = out + ((size_t)b * COUT + cout) * HWSZ + opos;
            #pragma unroll
            for (int r = 0; r < 4; ++r)
                op[(size_t)r * HWSZ] = acc[mt][nt][r];
        }
    }

    // ---- GN partial stats: wave wid's mt-subtile is exactly group wid*4+mt
    #pragma unroll
    for (int mt = 0; mt < 4; ++mt) {
        float s = 0.f, q = 0.f;
        #pragma unroll
        for (int nt = 0; nt < 4; ++nt)
            #pragma unroll
            for (int r = 0; r < 4; ++r) {
                const float v = acc[mt][nt][r];
                s += v; q += v * v;
            }
        #pragma unroll
        for (int o = 32; o > 0; o >>= 1) {
            s += __shfl_xor(s, o);
            q += __shfl_xor(q, o);
        }
        if (lane == 0) {
            const int bg = b * GN_G + wid * 4 + mt;
            part[((size_t)bg * NPB + pblk) * 2]     = s;
            part[((size_t)bg * NPB + pblk) * 2 + 1] = q;
        }
    }
}

// ---- reduce partials -> stats[bg] = {mean, var}; 256 threads, 4 per bg
__global__ void gn_final_kernel(const float* __restrict__ part, float* __restrict__ stats) {
    const int t  = threadIdx.x;
    const int bg = t >> 2;
    const int j  = t & 3;
    float s = 0.f, q = 0.f;
    for (int i = j; i < NPB; i += 4) {
        s += part[((size_t)bg * NPB + i) * 2];
        q += part[((size_t)bg * NPB + i) * 2 + 1];
    }
    s += __shfl_xor(s, 1); q += __shfl_xor(q, 1);
    s += __shfl_xor(s, 2); q += __shfl_xor(q, 2);
    if (j == 0) {
        const float invn = 1.f / (float)((COUT / GN_G) * HWSZ);
        const float mean = s * invn;
        stats[bg * 2]     = mean;
        stats[bg * 2 + 1] = q * invn - mean * mean;
    }
}

// ---- GroupNorm apply (in place)
__global__ __launch_bounds__(256)
void gn_apply_kernel(float* __restrict__ y, const float* __restrict__ stats,
                     const float* __restrict__ gamma, const float* __restrict__ beta) {
    const int i = blockIdx.x * 256 + threadIdx.x;       // float4 index
    const int e = i * 4;
    const int c  = (e / HWSZ) & (COUT - 1);
    const int bg = e / (HWSZ * (COUT / GN_G));
    const float mean = stats[bg * 2];
    const float var  = stats[bg * 2 + 1];
    const float inv  = rsqrtf(var + EPSV);
    const float sc = inv * gamma[c];
    const float sh = beta[c] - mean * sc;
    float4 v = ((float4*)y)[i];
    v.x = v.x * sc + sh;
    v.y = v.y * sc + sh;
    v.z = v.z * sc + sh;
    v.w = v.w * sc + sh;
    ((float4*)y)[i] = v;
}

extern "C" void kernel_launch(void* const* d_in, const int* in_sizes, int n_in,
                              void* d_out, int out_size, void* d_ws, size_t ws_size,
                              hipStream_t stream) {
    const float* x      = (const float*)d_in[0];
    const float* offset = (const float*)d_in[1];
    const float* mask   = (const float*)d_in[2];
    const float* weight = (const float*)d_in[3];
    const float* gamma  = (const float*)d_in[4];
    const float* beta   = (const float*)d_in[5];
    float* out = (float*)d_out;

    // ws: xn bf16 (18.9 MB) | wp bf16 (1.18 MB) | part (73.8 KB) | stats (512 B)
    ushort* xn    = (ushort*)d_ws;
    ushort* wp    = xn + (size_t)BATCH * HWSZ * CIN;
    float*  part  = (float*)(wp + (size_t)9 * CIN * COUT);
    float*  stats = part + (size_t)BATCH * GN_G * NPB * 2;

    {
        dim3 g(HWSZ / 64, CIN / 64, BATCH);
        nhwc_kernel<<<g, 256, 0, stream>>>(x, xn);
    }
    repack_w_kernel<<<9 * CIN * COUT / 256, 256, 0, stream>>>(weight, wp);

    dcn_mfma_kernel<<<NWG, 256, 0, stream>>>(xn, offset, mask, wp, out, part);

    gn_final_kernel<<<1, 256, 0, stream>>>(part, stats);
    gn_apply_kernel<<<(size_t)BATCH * COUT * HWSZ / 4 / 256, 256, 0, stream>>>(out, stats, gamma, beta);
}